// Round 3
// baseline (444.697 us; speedup 1.0000x reference)
//
#include <hip/hip_runtime.h>
#include <hip/hip_fp16.h>

#define NN 50000
#define NE 600000
#define NG 3
#define D  128
#define NI 4096
#define BW 1024                         // nodes per bucket
#define NBUCK 49                        // ceil(NN/BW)
#define NPAD (NBUCK * BW)               // padded node count (50176) for int4 deg reads
#define EPT_BIN 16
#define EPB_BIN (256 * EPT_BIN)         // 4096 edges per block
#define NBLK_BIN ((NE + EPB_BIN - 1) / EPB_BIN)   // 147
#define XCVT_BLKS 3125                  // NN*D/8 threads, 8 floats each
#define WCVT_BLKS 48
#define CNT_BLKS (NBLK_BIN * NG)        // 441
#define EPT_SC 8
#define NBLK_SC ((NE + 256 * EPT_SC - 1) / (256 * EPT_SC))   // 293

typedef _Float16 half8 __attribute__((ext_vector_type(8)));
typedef float floatx4 __attribute__((ext_vector_type(4)));

static __device__ __forceinline__ float wextract(unsigned int v) {
  unsigned short u = (unsigned short)(v >> 16);
  _Float16 h;
  __builtin_memcpy(&h, &u, 2);
  return (float)h;
}

// ---------------- fused prep: xcvt + wcvt + per-node degree count ----------------
// R12: count-pass now also does a per-NODE global atomicAdd (deg table, 600KB,
// L2-resident fire-and-forget). This lets csr read degrees directly and kills
// the bin_kernel + binned intermediate (7.2MB write + 2x read) entirely.

__global__ __launch_bounds__(256) void prep_kernel(
    const float* __restrict__ x, __half* __restrict__ xh,
    const float* __restrict__ W0, const float* __restrict__ W1, const float* __restrict__ W2,
    const float* __restrict__ W3, const float* __restrict__ W4, const float* __restrict__ W5,
    __half* __restrict__ Wf,
    const int* __restrict__ e0, const int* __restrict__ e1, const int* __restrict__ e2,
    int* __restrict__ bucketCnt, int* __restrict__ deg) {
  __shared__ int cnt[NBUCK];
  int blk = blockIdx.x;
  int tid = threadIdx.x;
  if (blk < XCVT_BLKS) {
    int i = blk * 256 + tid;
    size_t base = (size_t)i * 8;
    float4 v0 = *(const float4*)&x[base];
    float4 v1 = *(const float4*)&x[base + 4];
    half8 h;
    h[0] = (_Float16)v0.x; h[1] = (_Float16)v0.y; h[2] = (_Float16)v0.z; h[3] = (_Float16)v0.w;
    h[4] = (_Float16)v1.x; h[5] = (_Float16)v1.y; h[6] = (_Float16)v1.z; h[7] = (_Float16)v1.w;
    *(half8*)&xh[base] = h;
  } else if (blk < XCVT_BLKS + WCVT_BLKS) {
    const float* Wm[6] = {W0, W1, W2, W3, W4, W5};
    int t = (blk - XCVT_BLKS) * 256 + tid;     // 0 .. 6*2048-1
    int mat = t >> 11;
    int fr = (t >> 6) & 31;
    int lane = t & 63;
    int tt = fr >> 2, ks = fr & 3;
    int n = tt * 16 + (lane & 15);
    int kb = ks * 32 + (lane >> 4) * 8;
    const float* W = Wm[mat];
#pragma unroll
    for (int j = 0; j < 8; j++)
      Wf[(size_t)t * 8 + j] = __float2half(W[(kb + j) * 128 + n]);
  } else {
    int cb = blk - XCVT_BLKS - WCVT_BLKS;
    int g = cb / NBLK_BIN, eb = cb % NBLK_BIN;
    const int* ei = (g == 0) ? e0 : ((g == 1) ? e1 : e2);
    if (tid < NBUCK) cnt[tid] = 0;
    __syncthreads();
    int base = eb * EPB_BIN;
#pragma unroll
    for (int i = 0; i < EPT_BIN; i++) {
      int e = base + tid + i * 256;
      if (e < NE) {
        int dst = ei[NE + e];
        atomicAdd(&cnt[dst >> 10], 1);
        atomicAdd(&deg[g * NPAD + dst], 1);
      }
    }
    __syncthreads();
    if (tid < NBUCK) atomicAdd(&bucketCnt[g * NBUCK + tid], cnt[tid]);
  }
}

// wave-parallel exclusive scan of 49 bucket counts per graph
__global__ void bscan_kernel(const int* __restrict__ bucketCnt, int* __restrict__ bucketBase,
                             int* __restrict__ rp) {
  int g = threadIdx.x >> 6;
  int lane = threadIdx.x & 63;
  if (g >= NG) return;
  int v = (lane < NBUCK) ? bucketCnt[g * NBUCK + lane] : 0;
  int incl = v;
#pragma unroll
  for (int off = 1; off < 64; off <<= 1) {
    int t = __shfl_up(incl, off, 64);
    if (lane >= off) incl += t;
  }
  int ex = incl - v;
  if (lane < NBUCK) bucketBase[g * NBUCK + lane] = ex;
  if (lane == 0) rp[g * (NN + 1) + NN] = NE;
}

// csr: block scan of per-node degrees (read directly from global deg table)
// -> rp (row ptr), dinv (fp32), dinvh (fp16 for scatter packing), cur (cursor init)
__global__ __launch_bounds__(256) void csr_kernel(const int* __restrict__ deg,
    const int* __restrict__ bucketBase, int* __restrict__ rp, float* __restrict__ dinv,
    unsigned short* __restrict__ dinvh, int* __restrict__ cur) {
  __shared__ int wsum[4];
  int g = blockIdx.y, b = blockIdx.x;
  int tid = threadIdx.x;
  int node0 = b * BW;
  int bb = bucketBase[g * NBUCK + b];
  int4 dv = *(const int4*)&deg[(size_t)g * NPAD + node0 + tid * 4];
  int d0 = dv.x, d1 = dv.y, d2 = dv.z, d3 = dv.w;
  int s = d0 + d1 + d2 + d3;
  int lane = tid & 63;
  int incl = s;
#pragma unroll
  for (int off = 1; off < 64; off <<= 1) {
    int n = __shfl_up(incl, off, 64);
    if (lane >= off) incl += n;
  }
  if (lane == 63) wsum[tid >> 6] = incl;
  __syncthreads();
  int wbase = 0;
#pragma unroll
  for (int w = 0; w < 4; w++)
    if (w < (tid >> 6)) wbase += wsum[w];
  int ex = wbase + incl - s;
  int exs[4] = {ex, ex + d0, ex + d0 + d1, ex + d0 + d1 + d2};
  int ds[4] = {d0, d1, d2, d3};
#pragma unroll
  for (int k = 0; k < 4; k++) {
    int node = node0 + tid * 4 + k;
    if (node < NN) {
      int r = bb + exs[k];
      rp[g * (NN + 1) + node] = r;
      cur[g * NN + node] = r;
      float di = rsqrtf((float)ds[k] + 1.0f);   // deg incl. self loop
      dinv[g * NN + node] = di;
      _Float16 h = (_Float16)di;
      unsigned short u;
      __builtin_memcpy(&u, &h, 2);
      dinvh[g * NN + node] = u;
    }
  }
}

// scatter (replaces bin+fillp): per edge, rank via global cursor atomic, then
// write packed (src | fp16 dinv[src]) straight to its final CSR slot.
__global__ __launch_bounds__(256) void scatter_kernel(const int* __restrict__ e0,
    const int* __restrict__ e1, const int* __restrict__ e2,
    const unsigned short* __restrict__ dinvh, int* __restrict__ cur,
    unsigned int* __restrict__ colp) {
  int g = blockIdx.y;
  const int* ei = (g == 0) ? e0 : ((g == 1) ? e1 : e2);
  int e = (blockIdx.x * 256 + threadIdx.x) * EPT_SC;
  if (e >= NE) return;                      // NE % 8 == 0: all-or-nothing per thread
  int4 sa = *(const int4*)&ei[e];
  int4 sb = *(const int4*)&ei[e + 4];
  int4 da = *(const int4*)&ei[NE + e];
  int4 db = *(const int4*)&ei[NE + e + 4];
  int src[8] = {sa.x, sa.y, sa.z, sa.w, sb.x, sb.y, sb.z, sb.w};
  int dst[8] = {da.x, da.y, da.z, da.w, db.x, db.y, db.z, db.w};
  int rk[8];
#pragma unroll
  for (int j = 0; j < 8; j++) rk[j] = atomicAdd(&cur[g * NN + dst[j]], 1);
  unsigned int pw[8];
#pragma unroll
  for (int j = 0; j < 8; j++)
    pw[j] = (unsigned int)src[j] | ((unsigned int)dinvh[g * NN + src[j]] << 16);
  unsigned int* cg = colp + (size_t)g * NE;
#pragma unroll
  for (int j = 0; j < 8; j++) cg[rk[j]] = pw[j];
}

// ---------------- aggregation: one wave per 4 (node, branch) rows ----------------
// blockIdx.y = branch. 4 node-groups x 16 lanes; lane l16 owns features
// l16*8 .. l16*8+7 of its group's node (full 128-feature row per 16-lane group).
// Amortizes the per-node prologue 4x, loads the self row once, and needs no
// cross-lane reduction. R12 note: near the random-gather memory ceiling
// (~3.9 TB/s, FETCH ~181MB vs 12.8MB compulsory) — left unchanged this round.

__global__ __launch_bounds__(256) void aggb_kernel(
    const __half* __restrict__ srch, const int* __restrict__ rp,
    const unsigned int* __restrict__ colp, const float* __restrict__ dinv,
    const int* __restrict__ index, __half* __restrict__ tout, int nrows) {
  int b = blockIdx.y;
  int lane = threadIdx.x & 63;
  int grp = lane >> 4;            // node-group within wave
  int l16 = lane & 15;            // feature slot: features l16*8 .. +7
  int gb = grp << 4;              // group's lane base for shfl broadcast
  int wv = (blockIdx.x * 256 + threadIdx.x) >> 6;   // global wave id
  int w = wv * 4 + grp;           // output row this group owns
  int valid = (w < nrows);
  int wc = valid ? w : 0;
  int node = index ? index[wc] : wc;
  const _Float16* srcv = (const _Float16*)srch;
  const int* rpb = rp + b * (NN + 1);
  int s = rpb[node];
  int e = rpb[node + 1];
  int n = valid ? (e - s) : 0;
  float di = dinv[b * NN + node];
  half8 selfh = *(const half8*)&srcv[(size_t)node * D + l16 * 8];
  float a[8];
#pragma unroll
  for (int k = 0; k < 8; k++) a[k] = di * (float)selfh[k];
  // wave-max degree across the 4 groups (uniform loop bound -> no divergence)
  int nmax = n;
  nmax = max(nmax, __shfl_xor(nmax, 16, 64));
  nmax = max(nmax, __shfl_xor(nmax, 32, 64));
  const unsigned int* cp = colp + (size_t)b * NE;
  for (int j0 = 0; j0 < nmax; j0 += 16) {
    // each group loads up to 16 of its packed cols (64B coalesced per group)
    unsigned int c = (j0 + l16 < n) ? cp[s + j0 + l16] : 0u;
    int rem = nmax - j0;
    rem = (rem > 16) ? 16 : rem;
    for (int jj = 0; jj < rem; jj += 4) {
      unsigned int v0 = (unsigned int)__shfl((int)c, gb + jj + 0, 64);
      unsigned int v1 = (unsigned int)__shfl((int)c, gb + jj + 1, 64);
      unsigned int v2 = (unsigned int)__shfl((int)c, gb + jj + 2, 64);
      unsigned int v3 = (unsigned int)__shfl((int)c, gb + jj + 3, 64);
      half8 h0 = *(const half8*)&srcv[(size_t)(v0 & 0xffffu) * D + l16 * 8];
      half8 h1 = *(const half8*)&srcv[(size_t)(v1 & 0xffffu) * D + l16 * 8];
      half8 h2 = *(const half8*)&srcv[(size_t)(v2 & 0xffffu) * D + l16 * 8];
      half8 h3 = *(const half8*)&srcv[(size_t)(v3 & 0xffffu) * D + l16 * 8];
      float w0 = wextract(v0), w1 = wextract(v1);
      float w2 = wextract(v2), w3 = wextract(v3);
#pragma unroll
      for (int k = 0; k < 8; k++) a[k] = fmaf((float)h0[k], w0, a[k]);
#pragma unroll
      for (int k = 0; k < 8; k++) a[k] = fmaf((float)h1[k], w1, a[k]);
#pragma unroll
      for (int k = 0; k < 8; k++) a[k] = fmaf((float)h2[k], w2, a[k]);
#pragma unroll
      for (int k = 0; k < 8; k++) a[k] = fmaf((float)h3[k], w3, a[k]);
    }
  }
  if (valid) {
    half8 o;
#pragma unroll
    for (int k = 0; k < 8; k++) o[k] = (_Float16)(di * a[k]);
    _Float16* tv = (_Float16*)tout;
    *(half8*)&tv[(size_t)b * nrows * D + (size_t)w * D + l16 * 8] = o;
  }
}

// ---------------- fused 3-branch MFMA fp16 matmul + bias + relu + max ----------------
// A staged through LDS (coalesced global half8 loads, padded stride 136).

#define ALD 136   // padded LDS row stride (halves); 272B, 16B-aligned, conflict-light

__global__ __launch_bounds__(256) void mmf_kernel(const __half* __restrict__ A,
    const __half* __restrict__ Wf,
    const float* __restrict__ B0, const float* __restrict__ B1, const float* __restrict__ B2,
    __half* __restrict__ outh, float* __restrict__ outf, int M) {
  __shared__ _Float16 As[128 * ALD];  // 34.8 KB
  __shared__ _Float16 Ws[16384];      // 32 KB
  const float* Bb[3] = {B0, B1, B2};
  const int tid = threadIdx.x;
  const int wave = tid >> 6, lane = tid & 63;
  const int wr = (wave >> 1) * 64, wc = (wave & 1) * 64;
  const int ln = lane & 15, quad = lane >> 4;
  const int row0 = blockIdx.x * 128;
  float om[4][4][4];

  for (int b = 0; b < 3; b++) {
    const __half* Wb = Wf + (size_t)b * 16384;
#pragma unroll
    for (int i = 0; i < 8; i++) {
      int id = tid + i * 256;
      *(half8*)&Ws[id * 8] = *(const half8*)&Wb[(size_t)id * 8];
    }
    const __half* Ab = A + (size_t)b * M * D;
#pragma unroll
    for (int i = 0; i < 8; i++) {
      int idx = tid + i * 256;          // 0..2047 half8 slots
      int r = idx >> 4, c8 = idx & 15;
      int gr = row0 + r;
      gr = (gr < M) ? gr : (M - 1);
      half8 v = *(const half8*)&Ab[(size_t)gr * D + c8 * 8];
      *(half8*)&As[r * ALD + c8 * 8] = v;
    }
    __syncthreads();

    float bias[4];
#pragma unroll
    for (int ct = 0; ct < 4; ct++) bias[ct] = Bb[b][wc + ct * 16 + ln];
    floatx4 acc[4][4];
#pragma unroll
    for (int rt = 0; rt < 4; rt++)
#pragma unroll
      for (int ct = 0; ct < 4; ct++)
        acc[rt][ct] = (floatx4){bias[ct], bias[ct], bias[ct], bias[ct]};

#pragma unroll
    for (int ks = 0; ks < 4; ks++) {
      half8 av[4];
#pragma unroll
      for (int rt = 0; rt < 4; rt++)
        av[rt] = *(const half8*)&As[(wr + rt * 16 + ln) * ALD + ks * 32 + quad * 8];
#pragma unroll
      for (int ct = 0; ct < 4; ct++) {
        int tt = (wc >> 4) + ct;
        half8 bv = *(const half8*)&Ws[((tt * 4 + ks) * 64 + lane) * 8];
#pragma unroll
        for (int rt = 0; rt < 4; rt++)
          acc[rt][ct] = __builtin_amdgcn_mfma_f32_16x16x32_f16(av[rt], bv, acc[rt][ct], 0, 0, 0);
      }
    }
#pragma unroll
    for (int rt = 0; rt < 4; rt++)
#pragma unroll
      for (int ct = 0; ct < 4; ct++)
#pragma unroll
        for (int r = 0; r < 4; r++) {
          float v = fmaxf(acc[rt][ct][r], 0.f);
          om[rt][ct][r] = (b == 0) ? v : fmaxf(om[rt][ct][r], v);
        }
    __syncthreads();
  }
#pragma unroll
  for (int rt = 0; rt < 4; rt++) {
    int m = row0 + wr + rt * 16 + quad * 4;
#pragma unroll
    for (int r = 0; r < 4; r++) {
      if (m + r < M) {
#pragma unroll
        for (int ct = 0; ct < 4; ct++) {
          int n = wc + ct * 16 + ln;
          if (outh) outh[(size_t)(m + r) * D + n] = __float2half(om[rt][ct][r]);
          else      outf[(size_t)(m + r) * D + n] = om[rt][ct][r];
        }
      }
    }
  }
}

// ---------------- launch ----------------

extern "C" void kernel_launch(void* const* d_in, const int* in_sizes, int n_in,
                              void* d_out, int out_size, void* d_ws, size_t ws_size,
                              hipStream_t stream) {
  const float* x = (const float*)d_in[0];
  const int* e0 = (const int*)d_in[1];
  const int* e1 = (const int*)d_in[2];
  const int* e2 = (const int*)d_in[3];
  const int* index = (const int*)d_in[4];
  const float* w1[3] = {(const float*)d_in[5], (const float*)d_in[9],  (const float*)d_in[13]};
  const float* b1[3] = {(const float*)d_in[6], (const float*)d_in[10], (const float*)d_in[14]};
  const float* w2[3] = {(const float*)d_in[7], (const float*)d_in[11], (const float*)d_in[15]};
  const float* b2[3] = {(const float*)d_in[8], (const float*)d_in[12], (const float*)d_in[16]};
  float* out = (float*)d_out;

  char* ws = (char*)d_ws;
  size_t o = 0;
  auto alloc = [&](size_t bytes) {
    o = (o + 255) & ~(size_t)255;
    void* p = ws + o;
    o += bytes;
    return p;
  };
  int*    rp     = (int*)alloc((size_t)NG * (NN + 1) * 4);
  unsigned int* colp = (unsigned int*)alloc((size_t)NG * NE * 4);
  float*  dinv   = (float*)alloc((size_t)NG * NN * 4);
  unsigned short* dinvh = (unsigned short*)alloc((size_t)NG * NN * 2);
  // deg (padded) and bcnt contiguous -> single memset covers both
  int*    deg    = (int*)alloc((size_t)NG * NPAD * 4 + (size_t)NG * NBUCK * 4);
  int*    bcnt   = deg + (size_t)NG * NPAD;
  int*    bbase  = (int*)alloc((size_t)NG * NBUCK * 4);
  int*    cur    = (int*)alloc((size_t)NG * NN * 4);
  __half* xh     = (__half*)alloc((size_t)NN * D * 2);        // 12.8 MB
  __half* Wf     = (__half*)alloc((size_t)6 * 128 * 128 * 2); // 196 KB
  __half* t1     = (__half*)alloc((size_t)NG * NN * D * 2);   // 38.4 MB
  __half* hacc   = (__half*)alloc((size_t)NN * D * 2);        // 12.8 MB
  __half* t2     = t1;                       // alias: t1 free during layer 2
  (void)ws_size; (void)in_sizes; (void)n_in; (void)out_size;

  hipMemsetAsync(deg, 0, (size_t)NG * NPAD * 4 + (size_t)NG * NBUCK * 4, stream);
  prep_kernel<<<XCVT_BLKS + WCVT_BLKS + CNT_BLKS, 256, 0, stream>>>(
      x, xh, w1[0], w1[1], w1[2], w2[0], w2[1], w2[2], Wf, e0, e1, e2, bcnt, deg);
  bscan_kernel<<<1, 192, 0, stream>>>(bcnt, bbase, rp);
  csr_kernel<<<dim3(NBUCK, NG), 256, 0, stream>>>(deg, bbase, rp, dinv, dinvh, cur);
  scatter_kernel<<<dim3(NBLK_SC, NG), 256, 0, stream>>>(e0, e1, e2, dinvh, cur, colp);

  // layer 1: t1_b = Norm_b(xh);  hacc = max_b relu(t1_b @ W1_b + b1_b)   [fp16]
  aggb_kernel<<<dim3((NN + 15) / 16, NG), 256, 0, stream>>>(
      xh, rp, colp, dinv, nullptr, t1, NN);
  mmf_kernel<<<(NN + 127) / 128, 256, 0, stream>>>(t1, Wf, b1[0], b1[1], b1[2],
                                                   hacc, nullptr, NN);
  // layer 2: t2_b = Norm_b(hacc)[index];  out = max_b relu(t2_b @ W2_b + b2_b)
  aggb_kernel<<<dim3((NI + 15) / 16, NG), 256, 0, stream>>>(
      hacc, rp, colp, dinv, index, t2, NI);
  mmf_kernel<<<(NI + 127) / 128, 256, 0, stream>>>(t2, Wf + (size_t)3 * 16384,
                                                   b2[0], b2[1], b2[2], nullptr, out, NI);
}

// Round 4
// 344.076 us; speedup vs baseline: 1.2924x; 1.2924x over previous
//
#include <hip/hip_runtime.h>
#include <hip/hip_fp16.h>

#define NN 50000
#define NE 600000
#define NG 3
#define D  128
#define NI 4096
#define BW 1024                         // nodes per bucket
#define NBUCK 49                        // ceil(NN/BW)
#define NPAD (NBUCK * BW)               // padded node count (50176) for int4 deg reads
#define EPT_BIN 16
#define EPB_BIN (256 * EPT_BIN)         // 4096 edges per block
#define NBLK_BIN ((NE + EPB_BIN - 1) / EPB_BIN)   // 147
#define XCVT_BLKS 3125                  // NN*D/8 threads, 8 floats each
#define WCVT_BLKS 48
#define CNT_BLKS (NBLK_BIN * NG)        // 441
#define DINV_BLKS (NG * NBUCK)          // 147: one block per (graph,bucket), 1024 nodes

typedef _Float16 half8 __attribute__((ext_vector_type(8)));
typedef float floatx4 __attribute__((ext_vector_type(4)));

static __device__ __forceinline__ float wextract(unsigned int v) {
  unsigned short u = (unsigned short)(v >> 16);
  _Float16 h;
  __builtin_memcpy(&h, &u, 2);
  return (float)h;
}

static __device__ __forceinline__ unsigned short h16(float f) {
  _Float16 h = (_Float16)f;
  unsigned short u;
  __builtin_memcpy(&u, &h, 2);
  return u;
}

// ---------------- fused prep: xcvt + wcvt + per-node degree count ----------------
// R13: count pass = pure fire-and-forget global atomicAdd into per-node deg table
// (no return value -> no latency chain; 600KB/graph L2-resident). Bucket counts
// are derived later by dinvcnt_kernel's block reduction (removes LDS histogram).
// R12 LESSON (do not repeat): writing edges to final per-node CSR slots from an
// unsorted stream = 17x write amplification (122MB for 7.2MB logical). The
// bucket presort in bin_kernel is what gives the final scatter its locality.

__global__ __launch_bounds__(256) void prep_kernel(
    const float* __restrict__ x, __half* __restrict__ xh,
    const float* __restrict__ W0, const float* __restrict__ W1, const float* __restrict__ W2,
    const float* __restrict__ W3, const float* __restrict__ W4, const float* __restrict__ W5,
    __half* __restrict__ Wf,
    const int* __restrict__ e0, const int* __restrict__ e1, const int* __restrict__ e2,
    int* __restrict__ deg) {
  int blk = blockIdx.x;
  int tid = threadIdx.x;
  if (blk < XCVT_BLKS) {
    int i = blk * 256 + tid;
    size_t base = (size_t)i * 8;
    float4 v0 = *(const float4*)&x[base];
    float4 v1 = *(const float4*)&x[base + 4];
    half8 h;
    h[0] = (_Float16)v0.x; h[1] = (_Float16)v0.y; h[2] = (_Float16)v0.z; h[3] = (_Float16)v0.w;
    h[4] = (_Float16)v1.x; h[5] = (_Float16)v1.y; h[6] = (_Float16)v1.z; h[7] = (_Float16)v1.w;
    *(half8*)&xh[base] = h;
  } else if (blk < XCVT_BLKS + WCVT_BLKS) {
    const float* Wm[6] = {W0, W1, W2, W3, W4, W5};
    int t = (blk - XCVT_BLKS) * 256 + tid;     // 0 .. 6*2048-1
    int mat = t >> 11;
    int fr = (t >> 6) & 31;
    int lane = t & 63;
    int tt = fr >> 2, ks = fr & 3;
    int n = tt * 16 + (lane & 15);
    int kb = ks * 32 + (lane >> 4) * 8;
    const float* W = Wm[mat];
#pragma unroll
    for (int j = 0; j < 8; j++)
      Wf[(size_t)t * 8 + j] = __float2half(W[(kb + j) * 128 + n]);
  } else {
    int cb = blk - XCVT_BLKS - WCVT_BLKS;
    int g = cb / NBLK_BIN, eb = cb % NBLK_BIN;
    const int* ei = (g == 0) ? e0 : ((g == 1) ? e1 : e2);
    int* dg = deg + (size_t)g * NPAD;
    int base = eb * EPB_BIN;
#pragma unroll
    for (int i = 0; i < EPT_BIN; i++) {
      int e = base + tid + i * 256;
      if (e < NE) atomicAdd(&dg[ei[NE + e]], 1);
    }
  }
}

// one block per (graph,bucket): dinv fp32 + fp16 tables from deg, and block-reduce
// deg -> bucketCnt (direct store, no atomics: exactly one block owns each bucket).
__global__ __launch_bounds__(256) void dinvcnt_kernel(const int* __restrict__ deg,
    float* __restrict__ dinv, unsigned short* __restrict__ dinvh,
    int* __restrict__ bucketCnt) {
  __shared__ int wred[4];
  size_t base = (size_t)blockIdx.x * BW + threadIdx.x * 4;   // flat over NG*NPAD
  int4 dv = *(const int4*)&deg[base];
  float4 f;
  f.x = rsqrtf((float)dv.x + 1.0f);   // deg incl. self loop
  f.y = rsqrtf((float)dv.y + 1.0f);
  f.z = rsqrtf((float)dv.z + 1.0f);
  f.w = rsqrtf((float)dv.w + 1.0f);
  *(float4*)&dinv[base] = f;
  ushort4 u;
  u.x = h16(f.x); u.y = h16(f.y); u.z = h16(f.z); u.w = h16(f.w);
  *(ushort4*)&dinvh[base] = u;
  int s = dv.x + dv.y + dv.z + dv.w;
#pragma unroll
  for (int off = 32; off >= 1; off >>= 1) s += __shfl_down(s, off, 64);
  if ((threadIdx.x & 63) == 0) wred[threadIdx.x >> 6] = s;
  __syncthreads();
  if (threadIdx.x == 0)
    bucketCnt[blockIdx.x] = wred[0] + wred[1] + wred[2] + wred[3];  // layout == g*NBUCK+b
}

// wave-parallel exclusive scan of 49 bucket counts per graph
__global__ void bscan_kernel(const int* __restrict__ bucketCnt, int* __restrict__ bucketBase,
                             int* __restrict__ cursor, int* __restrict__ rp) {
  int g = threadIdx.x >> 6;
  int lane = threadIdx.x & 63;
  if (g >= NG) return;
  int v = (lane < NBUCK) ? bucketCnt[g * NBUCK + lane] : 0;
  int incl = v;
#pragma unroll
  for (int off = 1; off < 64; off <<= 1) {
    int t = __shfl_up(incl, off, 64);
    if (lane >= off) incl += t;
  }
  int ex = incl - v;
  if (lane < NBUCK) {
    bucketBase[g * NBUCK + lane] = ex;
    cursor[g * NBUCK + lane] = ex;
  }
  if (lane == 0) rp[g * (NN + 1) + NN] = NE;
}

// per-wave histograms to cut same-address LDS atomic serialization (unchanged R2)
__global__ __launch_bounds__(256) void bin_kernel(const int* __restrict__ e0,
    const int* __restrict__ e1, const int* __restrict__ e2,
    int* __restrict__ cursor, unsigned int* __restrict__ binned) {
  __shared__ int cnt[4][NBUCK];
  __shared__ int base[NBUCK];
  __shared__ int woff[4][NBUCK];
  int g = blockIdx.y;
  const int* ei = (g == 0) ? e0 : ((g == 1) ? e1 : e2);
  int tid = threadIdx.x;
  int wave = tid >> 6;
  if (tid < NBUCK) { cnt[0][tid] = 0; cnt[1][tid] = 0; cnt[2][tid] = 0; cnt[3][tid] = 0; }
  __syncthreads();
  int estart = blockIdx.x * EPB_BIN;
  int src[EPT_BIN], dst[EPT_BIN], rk[EPT_BIN];
#pragma unroll
  for (int i = 0; i < EPT_BIN; i++) {
    int e = estart + tid + i * 256;
    if (e < NE) {
      src[i] = ei[e];
      dst[i] = ei[NE + e];
      rk[i] = atomicAdd(&cnt[wave][dst[i] >> 10], 1);
    } else {
      rk[i] = -1;
    }
  }
  __syncthreads();
  if (tid < NBUCK) {
    int c0 = cnt[0][tid], c1 = cnt[1][tid], c2 = cnt[2][tid], c3 = cnt[3][tid];
    int total = c0 + c1 + c2 + c3;
    base[tid] = (total > 0) ? atomicAdd(&cursor[g * NBUCK + tid], total) : 0;
    woff[0][tid] = 0; woff[1][tid] = c0; woff[2][tid] = c0 + c1; woff[3][tid] = c0 + c1 + c2;
  }
  __syncthreads();
#pragma unroll
  for (int i = 0; i < EPT_BIN; i++) {
    if (rk[i] >= 0) {
      int b = dst[i] >> 10;
      binned[(size_t)g * NE + base[b] + woff[wave][b] + rk[i]] =
          (unsigned int)src[i] | ((unsigned int)dst[i] << 16);
    }
  }
}

// fused csr+fillp: scan per-node degrees (from global deg table) -> rp + LDS
// cursor, then scatter bucket-sorted binned edges into final packed colp slots.
// Writes stay within this bucket's ~48KB colp window -> full line utilization.
__global__ __launch_bounds__(256) void csrf_kernel(const unsigned int* __restrict__ binned,
    const int* __restrict__ bucketBase, const int* __restrict__ deg,
    const unsigned short* __restrict__ dinvh,
    int* __restrict__ rp, unsigned int* __restrict__ colp) {
  __shared__ int cur[BW];
  __shared__ int wsum[4];
  int g = blockIdx.y, b = blockIdx.x;
  int tid = threadIdx.x;
  int node0 = b * BW;
  int bb = bucketBase[g * NBUCK + b];
  int4 dv = *(const int4*)&deg[(size_t)g * NPAD + node0 + tid * 4];
  int d0 = dv.x, d1 = dv.y, d2 = dv.z, d3 = dv.w;
  int s = d0 + d1 + d2 + d3;
  int lane = tid & 63;
  int incl = s;
#pragma unroll
  for (int off = 1; off < 64; off <<= 1) {
    int n = __shfl_up(incl, off, 64);
    if (lane >= off) incl += n;
  }
  if (lane == 63) wsum[tid >> 6] = incl;
  __syncthreads();
  int wbase = 0;
#pragma unroll
  for (int w = 0; w < 4; w++)
    if (w < (tid >> 6)) wbase += wsum[w];
  int ex = wbase + incl - s;
  int exs[4] = {ex, ex + d0, ex + d0 + d1, ex + d0 + d1 + d2};
#pragma unroll
  for (int k = 0; k < 4; k++) {
    int node = node0 + tid * 4 + k;
    cur[tid * 4 + k] = bb + exs[k];
    if (node < NN) rp[g * (NN + 1) + node] = bb + exs[k];
  }
  int total = wsum[0] + wsum[1] + wsum[2] + wsum[3];
  __syncthreads();
  const unsigned int* bp = binned + (size_t)g * NE + bb;
  const unsigned short* dh = dinvh + (size_t)g * NPAD;
  unsigned int* cg = colp + (size_t)g * NE;
  for (int e = tid; e < total; e += 256) {
    unsigned int p = bp[e];
    int srcid = (int)(p & 0xffffu);
    int r = atomicAdd(&cur[(int)(p >> 16) - node0], 1);
    cg[r] = (unsigned int)srcid | ((unsigned int)dh[srcid] << 16);
  }
}

// ---------------- aggregation: one wave per 4 (node, branch) rows ----------------
// blockIdx.y = branch. 4 node-groups x 16 lanes; lane l16 owns features
// l16*8 .. l16*8+7 of its group's node (full 128-feature row per 16-lane group).
// Amortizes the per-node prologue 4x, loads the self row once, and needs no
// cross-lane reduction. Near the random-gather memory ceiling (~3.9 TB/s,
// FETCH ~181MB vs 12.8MB compulsory) — unchanged except dinv stride NN->NPAD.

__global__ __launch_bounds__(256) void aggb_kernel(
    const __half* __restrict__ srch, const int* __restrict__ rp,
    const unsigned int* __restrict__ colp, const float* __restrict__ dinv,
    const int* __restrict__ index, __half* __restrict__ tout, int nrows) {
  int b = blockIdx.y;
  int lane = threadIdx.x & 63;
  int grp = lane >> 4;            // node-group within wave
  int l16 = lane & 15;            // feature slot: features l16*8 .. +7
  int gb = grp << 4;              // group's lane base for shfl broadcast
  int wv = (blockIdx.x * 256 + threadIdx.x) >> 6;   // global wave id
  int w = wv * 4 + grp;           // output row this group owns
  int valid = (w < nrows);
  int wc = valid ? w : 0;
  int node = index ? index[wc] : wc;
  const _Float16* srcv = (const _Float16*)srch;
  const int* rpb = rp + b * (NN + 1);
  int s = rpb[node];
  int e = rpb[node + 1];
  int n = valid ? (e - s) : 0;
  float di = dinv[b * NPAD + node];
  half8 selfh = *(const half8*)&srcv[(size_t)node * D + l16 * 8];
  float a[8];
#pragma unroll
  for (int k = 0; k < 8; k++) a[k] = di * (float)selfh[k];
  // wave-max degree across the 4 groups (uniform loop bound -> no divergence)
  int nmax = n;
  nmax = max(nmax, __shfl_xor(nmax, 16, 64));
  nmax = max(nmax, __shfl_xor(nmax, 32, 64));
  const unsigned int* cp = colp + (size_t)b * NE;
  for (int j0 = 0; j0 < nmax; j0 += 16) {
    // each group loads up to 16 of its packed cols (64B coalesced per group)
    unsigned int c = (j0 + l16 < n) ? cp[s + j0 + l16] : 0u;
    int rem = nmax - j0;
    rem = (rem > 16) ? 16 : rem;
    for (int jj = 0; jj < rem; jj += 4) {
      unsigned int v0 = (unsigned int)__shfl((int)c, gb + jj + 0, 64);
      unsigned int v1 = (unsigned int)__shfl((int)c, gb + jj + 1, 64);
      unsigned int v2 = (unsigned int)__shfl((int)c, gb + jj + 2, 64);
      unsigned int v3 = (unsigned int)__shfl((int)c, gb + jj + 3, 64);
      half8 h0 = *(const half8*)&srcv[(size_t)(v0 & 0xffffu) * D + l16 * 8];
      half8 h1 = *(const half8*)&srcv[(size_t)(v1 & 0xffffu) * D + l16 * 8];
      half8 h2 = *(const half8*)&srcv[(size_t)(v2 & 0xffffu) * D + l16 * 8];
      half8 h3 = *(const half8*)&srcv[(size_t)(v3 & 0xffffu) * D + l16 * 8];
      float w0 = wextract(v0), w1 = wextract(v1);
      float w2 = wextract(v2), w3 = wextract(v3);
#pragma unroll
      for (int k = 0; k < 8; k++) a[k] = fmaf((float)h0[k], w0, a[k]);
#pragma unroll
      for (int k = 0; k < 8; k++) a[k] = fmaf((float)h1[k], w1, a[k]);
#pragma unroll
      for (int k = 0; k < 8; k++) a[k] = fmaf((float)h2[k], w2, a[k]);
#pragma unroll
      for (int k = 0; k < 8; k++) a[k] = fmaf((float)h3[k], w3, a[k]);
    }
  }
  if (valid) {
    half8 o;
#pragma unroll
    for (int k = 0; k < 8; k++) o[k] = (_Float16)(di * a[k]);
    _Float16* tv = (_Float16*)tout;
    *(half8*)&tv[(size_t)b * nrows * D + (size_t)w * D + l16 * 8] = o;
  }
}

// ---------------- fused 3-branch MFMA fp16 matmul + bias + relu + max ----------------
// A staged through LDS (coalesced global half8 loads, padded stride 136).

#define ALD 136   // padded LDS row stride (halves); 272B, 16B-aligned, conflict-light

__global__ __launch_bounds__(256) void mmf_kernel(const __half* __restrict__ A,
    const __half* __restrict__ Wf,
    const float* __restrict__ B0, const float* __restrict__ B1, const float* __restrict__ B2,
    __half* __restrict__ outh, float* __restrict__ outf, int M) {
  __shared__ _Float16 As[128 * ALD];  // 34.8 KB
  __shared__ _Float16 Ws[16384];      // 32 KB
  const float* Bb[3] = {B0, B1, B2};
  const int tid = threadIdx.x;
  const int wave = tid >> 6, lane = tid & 63;
  const int wr = (wave >> 1) * 64, wc = (wave & 1) * 64;
  const int ln = lane & 15, quad = lane >> 4;
  const int row0 = blockIdx.x * 128;
  float om[4][4][4];

  for (int b = 0; b < 3; b++) {
    const __half* Wb = Wf + (size_t)b * 16384;
#pragma unroll
    for (int i = 0; i < 8; i++) {
      int id = tid + i * 256;
      *(half8*)&Ws[id * 8] = *(const half8*)&Wb[(size_t)id * 8];
    }
    const __half* Ab = A + (size_t)b * M * D;
#pragma unroll
    for (int i = 0; i < 8; i++) {
      int idx = tid + i * 256;          // 0..2047 half8 slots
      int r = idx >> 4, c8 = idx & 15;
      int gr = row0 + r;
      gr = (gr < M) ? gr : (M - 1);
      half8 v = *(const half8*)&Ab[(size_t)gr * D + c8 * 8];
      *(half8*)&As[r * ALD + c8 * 8] = v;
    }
    __syncthreads();

    float bias[4];
#pragma unroll
    for (int ct = 0; ct < 4; ct++) bias[ct] = Bb[b][wc + ct * 16 + ln];
    floatx4 acc[4][4];
#pragma unroll
    for (int rt = 0; rt < 4; rt++)
#pragma unroll
      for (int ct = 0; ct < 4; ct++)
        acc[rt][ct] = (floatx4){bias[ct], bias[ct], bias[ct], bias[ct]};

#pragma unroll
    for (int ks = 0; ks < 4; ks++) {
      half8 av[4];
#pragma unroll
      for (int rt = 0; rt < 4; rt++)
        av[rt] = *(const half8*)&As[(wr + rt * 16 + ln) * ALD + ks * 32 + quad * 8];
#pragma unroll
      for (int ct = 0; ct < 4; ct++) {
        int tt = (wc >> 4) + ct;
        half8 bv = *(const half8*)&Ws[((tt * 4 + ks) * 64 + lane) * 8];
#pragma unroll
        for (int rt = 0; rt < 4; rt++)
          acc[rt][ct] = __builtin_amdgcn_mfma_f32_16x16x32_f16(av[rt], bv, acc[rt][ct], 0, 0, 0);
      }
    }
#pragma unroll
    for (int rt = 0; rt < 4; rt++)
#pragma unroll
      for (int ct = 0; ct < 4; ct++)
#pragma unroll
        for (int r = 0; r < 4; r++) {
          float v = fmaxf(acc[rt][ct][r], 0.f);
          om[rt][ct][r] = (b == 0) ? v : fmaxf(om[rt][ct][r], v);
        }
    __syncthreads();
  }
#pragma unroll
  for (int rt = 0; rt < 4; rt++) {
    int m = row0 + wr + rt * 16 + quad * 4;
#pragma unroll
    for (int r = 0; r < 4; r++) {
      if (m + r < M) {
#pragma unroll
        for (int ct = 0; ct < 4; ct++) {
          int n = wc + ct * 16 + ln;
          if (outh) outh[(size_t)(m + r) * D + n] = __float2half(om[rt][ct][r]);
          else      outf[(size_t)(m + r) * D + n] = om[rt][ct][r];
        }
      }
    }
  }
}

// ---------------- launch ----------------

extern "C" void kernel_launch(void* const* d_in, const int* in_sizes, int n_in,
                              void* d_out, int out_size, void* d_ws, size_t ws_size,
                              hipStream_t stream) {
  const float* x = (const float*)d_in[0];
  const int* e0 = (const int*)d_in[1];
  const int* e1 = (const int*)d_in[2];
  const int* e2 = (const int*)d_in[3];
  const int* index = (const int*)d_in[4];
  const float* w1[3] = {(const float*)d_in[5], (const float*)d_in[9],  (const float*)d_in[13]};
  const float* b1[3] = {(const float*)d_in[6], (const float*)d_in[10], (const float*)d_in[14]};
  const float* w2[3] = {(const float*)d_in[7], (const float*)d_in[11], (const float*)d_in[15]};
  const float* b2[3] = {(const float*)d_in[8], (const float*)d_in[12], (const float*)d_in[16]};
  float* out = (float*)d_out;

  char* ws = (char*)d_ws;
  size_t o = 0;
  auto alloc = [&](size_t bytes) {
    o = (o + 255) & ~(size_t)255;
    void* p = ws + o;
    o += bytes;
    return p;
  };
  int*    rp     = (int*)alloc((size_t)NG * (NN + 1) * 4);
  unsigned int* colp = (unsigned int*)alloc((size_t)NG * NE * 4);
  int*    deg    = (int*)alloc((size_t)NG * NPAD * 4);        // 1.8 MB (memset)
  float*  dinv   = (float*)alloc((size_t)NG * NPAD * 4);
  unsigned short* dinvh = (unsigned short*)alloc((size_t)NG * NPAD * 2);
  int*    bcnt   = (int*)alloc((size_t)NG * NBUCK * 4);
  int*    bbase  = (int*)alloc((size_t)NG * NBUCK * 4);
  int*    bcur   = (int*)alloc((size_t)NG * NBUCK * 4);
  __half* xh     = (__half*)alloc((size_t)NN * D * 2);        // 12.8 MB
  __half* Wf     = (__half*)alloc((size_t)6 * 128 * 128 * 2); // 196 KB
  __half* t1     = (__half*)alloc((size_t)NG * NN * D * 2);   // 38.4 MB
  __half* hacc   = (__half*)alloc((size_t)NN * D * 2);        // 12.8 MB
  unsigned int* binned = (unsigned int*)t1;  // alias: consumed by csrf before aggb writes t1
  __half* t2     = t1;                       // alias: t1 free during layer 2
  (void)ws_size; (void)in_sizes; (void)n_in; (void)out_size;

  hipMemsetAsync(deg, 0, (size_t)NG * NPAD * 4, stream);
  prep_kernel<<<XCVT_BLKS + WCVT_BLKS + CNT_BLKS, 256, 0, stream>>>(
      x, xh, w1[0], w1[1], w1[2], w2[0], w2[1], w2[2], Wf, e0, e1, e2, deg);
  dinvcnt_kernel<<<DINV_BLKS, 256, 0, stream>>>(deg, dinv, dinvh, bcnt);
  bscan_kernel<<<1, 192, 0, stream>>>(bcnt, bbase, bcur, rp);
  bin_kernel<<<dim3(NBLK_BIN, NG), 256, 0, stream>>>(e0, e1, e2, bcur, binned);
  csrf_kernel<<<dim3(NBUCK, NG), 256, 0, stream>>>(binned, bbase, deg, dinvh, rp, colp);

  // layer 1: t1_b = Norm_b(xh);  hacc = max_b relu(t1_b @ W1_b + b1_b)   [fp16]
  aggb_kernel<<<dim3((NN + 15) / 16, NG), 256, 0, stream>>>(
      xh, rp, colp, dinv, nullptr, t1, NN);
  mmf_kernel<<<(NN + 127) / 128, 256, 0, stream>>>(t1, Wf, b1[0], b1[1], b1[2],
                                                   hacc, nullptr, NN);
  // layer 2: t2_b = Norm_b(hacc)[index];  out = max_b relu(t2_b @ W2_b + b2_b)
  aggb_kernel<<<dim3((NI + 15) / 16, NG), 256, 0, stream>>>(
      hacc, rp, colp, dinv, index, t2, NI);
  mmf_kernel<<<(NI + 127) / 128, 256, 0, stream>>>(t2, Wf + (size_t)3 * 16384,
                                                   b2[0], b2[1], b2[2], nullptr, out, NI);
}

// Round 5
// 262.246 us; speedup vs baseline: 1.6957x; 1.3120x over previous
//
#include <hip/hip_runtime.h>
#include <hip/hip_fp16.h>

#define NN 50000
#define NE 600000
#define NG 3
#define D  128
#define NI 4096
#define BW 1024                         // nodes per bucket
#define NBUCK 49                        // ceil(NN/BW)
#define CAP 16384                       // slots per bucket (mean fill 12.3K, sigma~110)
#define REGION (NBUCK * CAP)            // 802816 slots per graph (< 2^20: rp32 packable)
#define EPT_BIN 16
#define EPB_BIN (256 * EPT_BIN)         // 4096 edges per block
#define NBLK_BIN ((NE + EPB_BIN - 1) / EPB_BIN)   // 147
#define XCVT_BLKS 3125                  // NN*D/8 threads, 8 floats each
#define WCVT_BLKS 48

typedef _Float16 half8 __attribute__((ext_vector_type(8)));
typedef float floatx4 __attribute__((ext_vector_type(4)));

static __device__ __forceinline__ float wextract(unsigned int v) {
  unsigned short u = (unsigned short)(v >> 16);
  _Float16 h;
  __builtin_memcpy(&h, &u, 2);
  return (float)h;
}

static __device__ __forceinline__ unsigned short h16(float f) {
  _Float16 h = (_Float16)f;
  unsigned short u;
  __builtin_memcpy(&u, &h, 2);
  return u;
}

// ---------------- fused prep: xcvt + wcvt + cursor init ----------------
// R14: count pass + bscan ELIMINATED. Buckets are oversized (CAP=16384 slots);
// bin_kernel self-allocates per-(block,bucket) chunks from gcur cursors, which
// are initialized here (one tiny branch block). No memset dispatch needed.
// R12 LESSON: never scatter 4B stores to final per-node CSR slots from an
// unsorted stream (17x write amplification) — bucket presort gives locality.
// R13 LESSON: never do per-edge random GLOBAL atomics (68MB write traffic for a
// 1.8MB table; cross-XCD line bouncing). LDS histogram + per-bucket atomics only.

__global__ __launch_bounds__(256) void prep_kernel(
    const float* __restrict__ x, __half* __restrict__ xh,
    const float* __restrict__ W0, const float* __restrict__ W1, const float* __restrict__ W2,
    const float* __restrict__ W3, const float* __restrict__ W4, const float* __restrict__ W5,
    __half* __restrict__ Wf, int* __restrict__ gcur) {
  int blk = blockIdx.x;
  int tid = threadIdx.x;
  if (blk < XCVT_BLKS) {
    int i = blk * 256 + tid;
    size_t base = (size_t)i * 8;
    float4 v0 = *(const float4*)&x[base];
    float4 v1 = *(const float4*)&x[base + 4];
    half8 h;
    h[0] = (_Float16)v0.x; h[1] = (_Float16)v0.y; h[2] = (_Float16)v0.z; h[3] = (_Float16)v0.w;
    h[4] = (_Float16)v1.x; h[5] = (_Float16)v1.y; h[6] = (_Float16)v1.z; h[7] = (_Float16)v1.w;
    *(half8*)&xh[base] = h;
  } else if (blk < XCVT_BLKS + WCVT_BLKS) {
    const float* Wm[6] = {W0, W1, W2, W3, W4, W5};
    int t = (blk - XCVT_BLKS) * 256 + tid;     // 0 .. 6*2048-1
    int mat = t >> 11;
    int fr = (t >> 6) & 31;
    int lane = t & 63;
    int tt = fr >> 2, ks = fr & 3;
    int n = tt * 16 + (lane & 15);
    int kb = ks * 32 + (lane >> 4) * 8;
    const float* W = Wm[mat];
#pragma unroll
    for (int j = 0; j < 8; j++)
      Wf[(size_t)t * 8 + j] = __float2half(W[(kb + j) * 128 + n]);
  } else {
    // cursor init: gcur[g*NBUCK+b] = b*CAP (completes before bin_kernel launches)
    if (tid < NG * NBUCK) gcur[tid] = (tid % NBUCK) * CAP;
  }
}

// per-wave LDS histograms (cuts same-address LDS atomic serialization 4x), then
// per-(block,bucket) contiguous chunk allocation straight from global cursors.
__global__ __launch_bounds__(256) void bin_kernel(const int* __restrict__ e0,
    const int* __restrict__ e1, const int* __restrict__ e2,
    int* __restrict__ gcur, unsigned int* __restrict__ binned) {
  __shared__ int cnt[4][NBUCK];
  __shared__ int base[NBUCK];
  __shared__ int woff[4][NBUCK];
  int g = blockIdx.y;
  const int* ei = (g == 0) ? e0 : ((g == 1) ? e1 : e2);
  int tid = threadIdx.x;
  int wave = tid >> 6;
  if (tid < NBUCK) { cnt[0][tid] = 0; cnt[1][tid] = 0; cnt[2][tid] = 0; cnt[3][tid] = 0; }
  __syncthreads();
  int estart = blockIdx.x * EPB_BIN;
  int src[EPT_BIN], dst[EPT_BIN], rk[EPT_BIN];
#pragma unroll
  for (int i = 0; i < EPT_BIN; i++) {
    int e = estart + tid + i * 256;
    if (e < NE) {
      src[i] = ei[e];
      dst[i] = ei[NE + e];
      rk[i] = atomicAdd(&cnt[wave][dst[i] >> 10], 1);
    } else {
      rk[i] = -1;
    }
  }
  __syncthreads();
  if (tid < NBUCK) {
    int c0 = cnt[0][tid], c1 = cnt[1][tid], c2 = cnt[2][tid], c3 = cnt[3][tid];
    int total = c0 + c1 + c2 + c3;
    base[tid] = (total > 0) ? atomicAdd(&gcur[g * NBUCK + tid], total) : 0;
    woff[0][tid] = 0; woff[1][tid] = c0; woff[2][tid] = c0 + c1; woff[3][tid] = c0 + c1 + c2;
  }
  __syncthreads();
#pragma unroll
  for (int i = 0; i < EPT_BIN; i++) {
    if (rk[i] >= 0) {
      int b = dst[i] >> 10;
      int pos = base[b] + woff[wave][b] + rk[i];
      if (pos < (b + 1) * CAP)   // overflow guard (never fires at CAP=16K, mean 12.3K)
        binned[(size_t)g * REGION + pos] =
            (unsigned int)src[i] | ((unsigned int)dst[i] << 16);
    }
  }
}

// csr: per-bucket degree histogram from binned -> packed rp32 (start | deg<<20),
// dinv fp32 (for aggb) and dinvh fp16 (for fillp's gather).
__global__ __launch_bounds__(256) void csr_kernel(const unsigned int* __restrict__ binned,
    const int* __restrict__ gcur, unsigned int* __restrict__ rp32,
    float* __restrict__ dinv, unsigned short* __restrict__ dinvh) {
  __shared__ int deg[BW];
  __shared__ int wsum[4];
  int g = blockIdx.y, b = blockIdx.x;
  int tid = threadIdx.x;
  int node0 = b * BW;
  int cbase = b * CAP;
  int total = min(gcur[g * NBUCK + b] - cbase, CAP);
  const unsigned int* bp = binned + (size_t)g * REGION + cbase;
  for (int i = tid; i < BW; i += 256) deg[i] = 0;
  __syncthreads();
  for (int e = tid; e < total; e += 256) {
    unsigned int p = bp[e];
    atomicAdd(&deg[(int)(p >> 16) - node0], 1);
  }
  __syncthreads();
  int d0 = deg[tid * 4], d1 = deg[tid * 4 + 1], d2 = deg[tid * 4 + 2], d3 = deg[tid * 4 + 3];
  int s = d0 + d1 + d2 + d3;
  int lane = tid & 63;
  int incl = s;
#pragma unroll
  for (int off = 1; off < 64; off <<= 1) {
    int n = __shfl_up(incl, off, 64);
    if (lane >= off) incl += n;
  }
  if (lane == 63) wsum[tid >> 6] = incl;
  __syncthreads();
  int wbase = 0;
#pragma unroll
  for (int w = 0; w < 4; w++)
    if (w < (tid >> 6)) wbase += wsum[w];
  int ex = wbase + incl - s;
  int exs[4] = {ex, ex + d0, ex + d0 + d1, ex + d0 + d1 + d2};
  int ds[4] = {d0, d1, d2, d3};
#pragma unroll
  for (int k = 0; k < 4; k++) {
    int node = node0 + tid * 4 + k;
    if (node < NN) {
      unsigned int st = (unsigned int)(cbase + exs[k]);
      rp32[g * NN + node] = st | ((unsigned int)ds[k] << 20);
      float di = rsqrtf((float)ds[k] + 1.0f);   // deg incl. self loop
      dinv[g * NN + node] = di;
      dinvh[g * NN + node] = h16(di);
    }
  }
}

// fillp: scatter packed (src | fp16 dinv[src]) into bucket-local colp slots.
// Writes stay within this bucket's 64KB window -> full line utilization.
__global__ __launch_bounds__(256) void fillp_kernel(const unsigned int* __restrict__ binned,
    const int* __restrict__ gcur, const unsigned int* __restrict__ rp32,
    const unsigned short* __restrict__ dinvh, unsigned int* __restrict__ colp) {
  __shared__ int cur[BW];
  int g = blockIdx.y, b = blockIdx.x;
  int tid = threadIdx.x;
  int node0 = b * BW;
  int cbase = b * CAP;
  int total = min(gcur[g * NBUCK + b] - cbase, CAP);
  const unsigned int* bp = binned + (size_t)g * REGION + cbase;
  for (int i = tid; i < BW; i += 256) {
    int node = node0 + i;
    cur[i] = (node < NN) ? (int)(rp32[g * NN + node] & 0xFFFFFu) : 0;
  }
  __syncthreads();
  const unsigned short* dh = dinvh + (size_t)g * NN;
  unsigned int* cg = colp + (size_t)g * REGION;
  for (int e = tid; e < total; e += 256) {
    unsigned int p = bp[e];
    int srcid = (int)(p & 0xffffu);
    int r = atomicAdd(&cur[(int)(p >> 16) - node0], 1);
    cg[r] = (unsigned int)srcid | ((unsigned int)dh[srcid] << 16);
  }
}

// ---------------- aggregation: one wave per 4 (node, branch) rows ----------------
// blockIdx.y = branch. 4 node-groups x 16 lanes; lane l16 owns features
// l16*8 .. l16*8+7 of its group's node (full 128-feature row per 16-lane group).
// Amortizes the per-node prologue 4x, loads the self row once, and needs no
// cross-lane reduction. R14: single packed rp32 load (start|deg) removes one
// dependent gather from the prologue latency chain. Near the random-gather
// memory ceiling (~3.9 TB/s L2-miss BW, FETCH ~181MB vs 12.8MB compulsory).

__global__ __launch_bounds__(256) void aggb_kernel(
    const __half* __restrict__ srch, const unsigned int* __restrict__ rp32,
    const unsigned int* __restrict__ colp, const float* __restrict__ dinv,
    const int* __restrict__ index, __half* __restrict__ tout, int nrows) {
  int b = blockIdx.y;
  int lane = threadIdx.x & 63;
  int grp = lane >> 4;            // node-group within wave
  int l16 = lane & 15;            // feature slot: features l16*8 .. +7
  int gb = grp << 4;              // group's lane base for shfl broadcast
  int wv = (blockIdx.x * 256 + threadIdx.x) >> 6;   // global wave id
  int w = wv * 4 + grp;           // output row this group owns
  int valid = (w < nrows);
  int wc = valid ? w : 0;
  int node = index ? index[wc] : wc;
  const _Float16* srcv = (const _Float16*)srch;
  unsigned int r32 = rp32[(size_t)b * NN + node];
  int s = (int)(r32 & 0xFFFFFu);
  int n = valid ? (int)(r32 >> 20) : 0;
  float di = dinv[b * NN + node];
  half8 selfh = *(const half8*)&srcv[(size_t)node * D + l16 * 8];
  float a[8];
#pragma unroll
  for (int k = 0; k < 8; k++) a[k] = di * (float)selfh[k];
  // wave-max degree across the 4 groups (uniform loop bound -> no divergence)
  int nmax = n;
  nmax = max(nmax, __shfl_xor(nmax, 16, 64));
  nmax = max(nmax, __shfl_xor(nmax, 32, 64));
  const unsigned int* cp = colp + (size_t)b * REGION;
  for (int j0 = 0; j0 < nmax; j0 += 16) {
    // each group loads up to 16 of its packed cols (64B coalesced per group)
    unsigned int c = (j0 + l16 < n) ? cp[s + j0 + l16] : 0u;
    int rem = nmax - j0;
    rem = (rem > 16) ? 16 : rem;
    for (int jj = 0; jj < rem; jj += 4) {
      unsigned int v0 = (unsigned int)__shfl((int)c, gb + jj + 0, 64);
      unsigned int v1 = (unsigned int)__shfl((int)c, gb + jj + 1, 64);
      unsigned int v2 = (unsigned int)__shfl((int)c, gb + jj + 2, 64);
      unsigned int v3 = (unsigned int)__shfl((int)c, gb + jj + 3, 64);
      half8 h0 = *(const half8*)&srcv[(size_t)(v0 & 0xffffu) * D + l16 * 8];
      half8 h1 = *(const half8*)&srcv[(size_t)(v1 & 0xffffu) * D + l16 * 8];
      half8 h2 = *(const half8*)&srcv[(size_t)(v2 & 0xffffu) * D + l16 * 8];
      half8 h3 = *(const half8*)&srcv[(size_t)(v3 & 0xffffu) * D + l16 * 8];
      float w0 = wextract(v0), w1 = wextract(v1);
      float w2 = wextract(v2), w3 = wextract(v3);
#pragma unroll
      for (int k = 0; k < 8; k++) a[k] = fmaf((float)h0[k], w0, a[k]);
#pragma unroll
      for (int k = 0; k < 8; k++) a[k] = fmaf((float)h1[k], w1, a[k]);
#pragma unroll
      for (int k = 0; k < 8; k++) a[k] = fmaf((float)h2[k], w2, a[k]);
#pragma unroll
      for (int k = 0; k < 8; k++) a[k] = fmaf((float)h3[k], w3, a[k]);
    }
  }
  if (valid) {
    half8 o;
#pragma unroll
    for (int k = 0; k < 8; k++) o[k] = (_Float16)(di * a[k]);
    _Float16* tv = (_Float16*)tout;
    *(half8*)&tv[(size_t)b * nrows * D + (size_t)w * D + l16 * 8] = o;
  }
}

// ---------------- fused 3-branch MFMA fp16 matmul + bias + relu + max ----------------
// A staged through LDS (coalesced global half8 loads, padded stride 136).

#define ALD 136   // padded LDS row stride (halves); 272B, 16B-aligned, conflict-light

__global__ __launch_bounds__(256) void mmf_kernel(const __half* __restrict__ A,
    const __half* __restrict__ Wf,
    const float* __restrict__ B0, const float* __restrict__ B1, const float* __restrict__ B2,
    __half* __restrict__ outh, float* __restrict__ outf, int M) {
  __shared__ _Float16 As[128 * ALD];  // 34.8 KB
  __shared__ _Float16 Ws[16384];      // 32 KB
  const float* Bb[3] = {B0, B1, B2};
  const int tid = threadIdx.x;
  const int wave = tid >> 6, lane = tid & 63;
  const int wr = (wave >> 1) * 64, wc = (wave & 1) * 64;
  const int ln = lane & 15, quad = lane >> 4;
  const int row0 = blockIdx.x * 128;
  float om[4][4][4];

  for (int b = 0; b < 3; b++) {
    const __half* Wb = Wf + (size_t)b * 16384;
#pragma unroll
    for (int i = 0; i < 8; i++) {
      int id = tid + i * 256;
      *(half8*)&Ws[id * 8] = *(const half8*)&Wb[(size_t)id * 8];
    }
    const __half* Ab = A + (size_t)b * M * D;
#pragma unroll
    for (int i = 0; i < 8; i++) {
      int idx = tid + i * 256;          // 0..2047 half8 slots
      int r = idx >> 4, c8 = idx & 15;
      int gr = row0 + r;
      gr = (gr < M) ? gr : (M - 1);
      half8 v = *(const half8*)&Ab[(size_t)gr * D + c8 * 8];
      *(half8*)&As[r * ALD + c8 * 8] = v;
    }
    __syncthreads();

    float bias[4];
#pragma unroll
    for (int ct = 0; ct < 4; ct++) bias[ct] = Bb[b][wc + ct * 16 + ln];
    floatx4 acc[4][4];
#pragma unroll
    for (int rt = 0; rt < 4; rt++)
#pragma unroll
      for (int ct = 0; ct < 4; ct++)
        acc[rt][ct] = (floatx4){bias[ct], bias[ct], bias[ct], bias[ct]};

#pragma unroll
    for (int ks = 0; ks < 4; ks++) {
      half8 av[4];
#pragma unroll
      for (int rt = 0; rt < 4; rt++)
        av[rt] = *(const half8*)&As[(wr + rt * 16 + ln) * ALD + ks * 32 + quad * 8];
#pragma unroll
      for (int ct = 0; ct < 4; ct++) {
        int tt = (wc >> 4) + ct;
        half8 bv = *(const half8*)&Ws[((tt * 4 + ks) * 64 + lane) * 8];
#pragma unroll
        for (int rt = 0; rt < 4; rt++)
          acc[rt][ct] = __builtin_amdgcn_mfma_f32_16x16x32_f16(av[rt], bv, acc[rt][ct], 0, 0, 0);
      }
    }
#pragma unroll
    for (int rt = 0; rt < 4; rt++)
#pragma unroll
      for (int ct = 0; ct < 4; ct++)
#pragma unroll
        for (int r = 0; r < 4; r++) {
          float v = fmaxf(acc[rt][ct][r], 0.f);
          om[rt][ct][r] = (b == 0) ? v : fmaxf(om[rt][ct][r], v);
        }
    __syncthreads();
  }
#pragma unroll
  for (int rt = 0; rt < 4; rt++) {
    int m = row0 + wr + rt * 16 + quad * 4;
#pragma unroll
    for (int r = 0; r < 4; r++) {
      if (m + r < M) {
#pragma unroll
        for (int ct = 0; ct < 4; ct++) {
          int n = wc + ct * 16 + ln;
          if (outh) outh[(size_t)(m + r) * D + n] = __float2half(om[rt][ct][r]);
          else      outf[(size_t)(m + r) * D + n] = om[rt][ct][r];
        }
      }
    }
  }
}

// ---------------- launch ----------------

extern "C" void kernel_launch(void* const* d_in, const int* in_sizes, int n_in,
                              void* d_out, int out_size, void* d_ws, size_t ws_size,
                              hipStream_t stream) {
  const float* x = (const float*)d_in[0];
  const int* e0 = (const int*)d_in[1];
  const int* e1 = (const int*)d_in[2];
  const int* e2 = (const int*)d_in[3];
  const int* index = (const int*)d_in[4];
  const float* w1[3] = {(const float*)d_in[5], (const float*)d_in[9],  (const float*)d_in[13]};
  const float* b1[3] = {(const float*)d_in[6], (const float*)d_in[10], (const float*)d_in[14]};
  const float* w2[3] = {(const float*)d_in[7], (const float*)d_in[11], (const float*)d_in[15]};
  const float* b2[3] = {(const float*)d_in[8], (const float*)d_in[12], (const float*)d_in[16]};
  float* out = (float*)d_out;

  char* ws = (char*)d_ws;
  size_t o = 0;
  auto alloc = [&](size_t bytes) {
    o = (o + 255) & ~(size_t)255;
    void* p = ws + o;
    o += bytes;
    return p;
  };
  unsigned int* rp32 = (unsigned int*)alloc((size_t)NG * NN * 4);
  unsigned int* colp = (unsigned int*)alloc((size_t)NG * REGION * 4);   // 9.6 MB
  float*  dinv   = (float*)alloc((size_t)NG * NN * 4);
  unsigned short* dinvh = (unsigned short*)alloc((size_t)NG * NN * 2);
  int*    gcur   = (int*)alloc((size_t)NG * NBUCK * 4);
  __half* xh     = (__half*)alloc((size_t)NN * D * 2);        // 12.8 MB
  __half* Wf     = (__half*)alloc((size_t)6 * 128 * 128 * 2); // 196 KB
  __half* t1     = (__half*)alloc((size_t)NG * NN * D * 2);   // 38.4 MB
  __half* hacc   = (__half*)alloc((size_t)NN * D * 2);        // 12.8 MB
  unsigned int* binned = (unsigned int*)t1;  // alias: consumed by csr/fillp before aggb writes t1
  __half* t2     = t1;                       // alias: t1 free during layer 2
  (void)ws_size; (void)in_sizes; (void)n_in; (void)out_size;

  prep_kernel<<<XCVT_BLKS + WCVT_BLKS + 1, 256, 0, stream>>>(
      x, xh, w1[0], w1[1], w1[2], w2[0], w2[1], w2[2], Wf, gcur);
  bin_kernel<<<dim3(NBLK_BIN, NG), 256, 0, stream>>>(e0, e1, e2, gcur, binned);
  csr_kernel<<<dim3(NBUCK, NG), 256, 0, stream>>>(binned, gcur, rp32, dinv, dinvh);
  fillp_kernel<<<dim3(NBUCK, NG), 256, 0, stream>>>(binned, gcur, rp32, dinvh, colp);

  // layer 1: t1_b = Norm_b(xh);  hacc = max_b relu(t1_b @ W1_b + b1_b)   [fp16]
  aggb_kernel<<<dim3((NN + 15) / 16, NG), 256, 0, stream>>>(
      xh, rp32, colp, dinv, nullptr, t1, NN);
  mmf_kernel<<<(NN + 127) / 128, 256, 0, stream>>>(t1, Wf, b1[0], b1[1], b1[2],
                                                   hacc, nullptr, NN);
  // layer 2: t2_b = Norm_b(hacc)[index];  out = max_b relu(t2_b @ W2_b + b2_b)
  aggb_kernel<<<dim3((NI + 15) / 16, NG), 256, 0, stream>>>(
      hacc, rp32, colp, dinv, index, t2, NI);
  mmf_kernel<<<(NI + 127) / 128, 256, 0, stream>>>(t2, Wf + (size_t)3 * 16384,
                                                   b2[0], b2[1], b2[2], nullptr, out, NI);
}